// Round 10
// baseline (383.507 us; speedup 1.0000x reference)
//
#include <hip/hip_runtime.h>
#include <cstdint>
#include <cstddef>

typedef _Float16 f16x8 __attribute__((ext_vector_type(8)));
typedef _Float16 f16x4 __attribute__((ext_vector_type(4)));
typedef float f32x4 __attribute__((ext_vector_type(4)));

static __device__ __forceinline__ float elu_f(float t) {
    return t > 0.0f ? t : expm1f(t);
}

// XCD-aware block -> pooled-vertex-tile remap (XCD = bid & 7 round-robin).
static __device__ __forceinline__ int block_pu0(int bid, int P, int vshift_out, int nbl)
{
    if (nbl < 0) return bid * P;
    int xcd  = bid & 7;
    int slot = bid >> 3;
    int nb   = slot & ((1 << nbl) - 1);
    int tile = slot >> nbl;
    return ((xcd + (nb << 3)) << vshift_out) + tile * P;
}

// ---------------- weight prep: fp32 [K][C_OUT] -> fp16 tiled [y][t][kc][n][8] ----------------
template<int KTOT, int C_OUT, int BN>
__global__ __launch_bounds__(256)
void prep_w(const float* __restrict__ W, _Float16* __restrict__ o)
{
    constexpr int KT = KTOT/64;
    int i = blockIdx.x * 256 + threadIdx.x;
    if (i >= KTOT*C_OUT) return;
    int j = i & 7;
    int rest = i >> 3;
    int n = rest % BN;
    int kc = (rest / BN) & 7;
    int t = (rest / (BN*8)) % KT;
    int y = rest / (BN*8*KT);
    int k = t*64 + kc*8 + j;
    o[i] = (_Float16)W[(size_t)k*C_OUT + y*BN + n];
}

// Level-0 weights: (36,32) -> padded K=64, k = s*4 + c layout, tile [kc][n][8]
__global__ __launch_bounds__(256)
void prep_w0(const float* __restrict__ W, _Float16* __restrict__ o)
{
    int i = blockIdx.x * 256 + threadIdx.x;
    if (i >= 2048) return;
    int j = i & 7;
    int n = (i >> 3) & 31;
    int kc = i >> 8;
    int k = kc*8 + j;
    int s = k >> 2, c = k & 3;
    float v = (s < 12 && c < 3) ? W[(size_t)(s*3 + c)*32 + n] : 0.0f;
    o[i] = (_Float16)v;
}

// ---------------- x transpose: (16,32768,3) fp32 -> (32768,16,4) fp16 ----------------
__global__ __launch_bounds__(256)
void prep_xT(const float* __restrict__ x, _Float16* __restrict__ xT)
{
    __shared__ _Float16 t[16][64*4 + 8];
    const int v0 = blockIdx.x * 64;
    const int tid = threadIdx.x;
    #pragma unroll
    for (int it = 0; it < 4; ++it) {
        int e = it*256 + tid;          // 16 b x 64 v
        int b = e >> 6, v = e & 63;
        const float* p = x + ((size_t)b*32768 + v0 + v)*3;
        f16x4 h;
        h[0] = (_Float16)p[0]; h[1] = (_Float16)p[1];
        h[2] = (_Float16)p[2]; h[3] = (_Float16)0.f;
        *(f16x4*)&t[b][v*4] = h;
    }
    __syncthreads();
    #pragma unroll
    for (int it = 0; it < 2; ++it) {
        int e = it*256 + tid;          // 64 v x 8 s
        int vl = e >> 3, s = e & 7;
        f16x4 a = *(const f16x4*)&t[2*s][vl*4];
        f16x4 b = *(const f16x4*)&t[2*s+1][vl*4];
        f16x8 h;
        h[0]=a[0]; h[1]=a[1]; h[2]=a[2]; h[3]=a[3];
        h[4]=b[0]; h[5]=b[1]; h[6]=b[2]; h[7]=b[3];
        *(f16x8*)&xT[((size_t)(v0+vl)*16 + s*2)*4] = h;
    }
}

// ---------------- index pre-compose: didx0 o spiral0 -> u16-pair table ----------------
__global__ __launch_bounds__(256)
void prep_gidx(const int* __restrict__ didx, const int* __restrict__ spiral,
               unsigned int* __restrict__ g)
{
    int i = blockIdx.x*256 + threadIdx.x;   // 24576 rows x 8
    if (i >= 24576*8) return;
    int q = i & 7;
    int row = i >> 3;
    unsigned int val = 0;
    if (q < 6) {
        int v = didx[row];
        unsigned int s0 = (unsigned int)spiral[v*12 + q*2];
        unsigned int s1 = (unsigned int)spiral[v*12 + q*2 + 1];
        val = s0 | (s1 << 16);
    }
    g[i] = val;
}

// ---------------- conv0+pool0, batched-M over 16 batches ----------------
__global__ __launch_bounds__(256)
void conv0T(const _Float16* __restrict__ xT, const unsigned int* __restrict__ gidx,
            const _Float16* __restrict__ Wp, const float* __restrict__ bias,
            const float* __restrict__ dwt, _Float16* __restrict__ out)
{
    __shared__ _Float16 Ep[4][512];        // per-wave 1 KB transpose buffer
    const int tid  = threadIdx.x;
    const int wave = tid >> 6;
    const int lane = tid & 63;
    const int quad = lane >> 4;
    const int l16  = lane & 15;
    const int u0   = blockIdx.x * 8 + wave * 2;   // 2 u per wave

    f16x8 bf[2][2];
    #pragma unroll
    for (int kt = 0; kt < 2; ++kt)
        #pragma unroll
        for (int nt = 0; nt < 2; ++nt)
            bf[kt][nt] = *(const f16x8*)&Wp[(((kt*4+quad)*32) + nt*16 + l16)*8];
    float bv[2] = { bias[l16], bias[16 + l16] };

    #pragma unroll
    for (int ui = 0; ui < 2; ++ui) {
        int u = u0 + ui;
        f32x4 pacc[2] = {{0.f,0.f,0.f,0.f},{0.f,0.f,0.f,0.f}};
        #pragma unroll
        for (int kp = 0; kp < 3; ++kp) {
            int r = u*3 + kp;
            unsigned int gp0 = gidx[r*8 + quad];
            unsigned int gp1 = gidx[r*8 + 4 + quad];
            f16x4 a0 = *(const f16x4*)&xT[(size_t)(gp0 & 0xffffu)*64 + l16*4];
            f16x4 a1 = *(const f16x4*)&xT[(size_t)(gp0 >> 16)*64 + l16*4];
            f16x4 a2 = *(const f16x4*)&xT[(size_t)(gp1 & 0xffffu)*64 + l16*4];
            f16x4 a3 = *(const f16x4*)&xT[(size_t)(gp1 >> 16)*64 + l16*4];
            f16x8 af0, af1;
            af0[0]=a0[0]; af0[1]=a0[1]; af0[2]=a0[2]; af0[3]=a0[3];
            af0[4]=a1[0]; af0[5]=a1[1]; af0[6]=a1[2]; af0[7]=a1[3];
            af1[0]=a2[0]; af1[1]=a2[1]; af1[2]=a2[2]; af1[3]=a2[3];
            af1[4]=a3[0]; af1[5]=a3[1]; af1[6]=a3[2]; af1[7]=a3[3];
            float dw = dwt[r];
            #pragma unroll
            for (int nt = 0; nt < 2; ++nt) {
                f32x4 m = {0.f,0.f,0.f,0.f};
                m = __builtin_amdgcn_mfma_f32_16x16x32_f16(af0, bf[0][nt], m, 0,0,0);
                m = __builtin_amdgcn_mfma_f32_16x16x32_f16(af1, bf[1][nt], m, 0,0,0);
                #pragma unroll
                for (int rr = 0; rr < 4; ++rr)
                    pacc[nt][rr] += dw * elu_f(m[rr] + bv[nt]);
            }
        }
        #pragma unroll
        for (int nt = 0; nt < 2; ++nt)
            #pragma unroll
            for (int rr = 0; rr < 4; ++rr)
                Ep[wave][(quad*4+rr)*32 + nt*16 + l16] = (_Float16)pacc[nt][rr];
        int b  = lane >> 2;
        int c8 = lane & 3;
        f16x8 rowv = *(const f16x8*)&Ep[wave][b*32 + c8*8];
        *(f16x8*)&out[(size_t)b*262144 + (size_t)u*32 + c8*8] = rowv;
    }
}

// ---------------- fused conv+pool, direct-to-register MFMA, levels 1-3 ----------------
template<int C_IN, int C_OUT, int P, int BN, int WGM, int WGN, bool OUT_HALF>
__global__ __launch_bounds__(256)
void conv_pool_mfma(const _Float16* __restrict__ x, const int* __restrict__ spiral,
                    const _Float16* __restrict__ Wp, const float* __restrict__ bias,
                    const int* __restrict__ didx, const float* __restrict__ dwt,
                    void* __restrict__ outv, int vshift_in, int vshift_out, int nbl)
{
    constexpr int R    = 3*P;
    constexpr int KTOT = 12*C_IN;
    constexpr int KT   = KTOT/64;
    constexpr int WTM  = R/WGM;
    constexpr int WTN  = BN/WGN;
    constexpr int NMT  = WTM/16;
    constexpr int NNT  = WTN/16;
    constexpr int C4   = BN/4;
    static_assert(WTM % 16 == 0 && WTN % 16 == 0, "tile");
    static_assert(R <= 256 && (P*C4) % 256 == 0, "loops");

    __shared__ unsigned short gidx[R*12];
    __shared__ _Float16 E[R*(BN+4)];

    const int tid  = threadIdx.x;
    const int wave = tid >> 6;
    const int lane = tid & 63;
    const int quad = lane >> 4;
    const int l16  = lane & 15;
    const int wm   = wave / WGN;
    const int wn   = wave % WGN;
    const int pu0  = block_pu0(blockIdx.x, P, vshift_out, nbl);
    const int n0   = blockIdx.y * BN;
    const int vmask_out = (1 << vshift_out) - 1;
    const int base_in = (pu0 >> vshift_out) << vshift_in;

    if (tid < R) {
        int ul = tid / 3;
        int kp = tid - ul*3;
        int u  = (pu0 + ul) & vmask_out;
        int v  = didx[u*3 + kp];
        const int* svp = spiral + v*12;
        #pragma unroll
        for (int j = 0; j < 12; ++j) gidx[tid*12 + j] = (unsigned short)svp[j];
    }
    __syncthreads();

    f32x4 acc[NMT][NNT];
    #pragma unroll
    for (int i = 0; i < NMT; ++i)
        #pragma unroll
        for (int j = 0; j < NNT; ++j) acc[i][j] = (f32x4){0.f, 0.f, 0.f, 0.f};

    const _Float16* xb = x + (size_t)base_in * C_IN;

    for (int t = 0; t < KT; ++t) {
        #pragma unroll
        for (int kt = 0; kt < 2; ++kt) {
            const int k0 = t*64 + kt*32;
            const int s  = k0 / C_IN;
            const int c  = (k0 & (C_IN-1)) + quad*8;
            f16x8 af[NMT];
            #pragma unroll
            for (int i = 0; i < NMT; ++i) {
                int m_local = wm*WTM + i*16 + l16;
                int g = gidx[m_local*12 + s];
                af[i] = *(const f16x8*)&xb[(size_t)g*C_IN + c];
            }
            const _Float16* wsrc = Wp + ((size_t)((blockIdx.y*KT + t)*8 + kt*4 + quad))*BN*8;
            f16x8 bf[NNT];
            #pragma unroll
            for (int j = 0; j < NNT; ++j) {
                int n_local = wn*WTN + j*16 + l16;
                bf[j] = *(const f16x8*)&wsrc[n_local*8];
            }
            #pragma unroll
            for (int i = 0; i < NMT; ++i)
                #pragma unroll
                for (int j = 0; j < NNT; ++j)
                    acc[i][j] = __builtin_amdgcn_mfma_f32_16x16x32_f16(
                        af[i], bf[j], acc[i][j], 0, 0, 0);
        }
    }

    float bv[NNT];
    #pragma unroll
    for (int j = 0; j < NNT; ++j)
        bv[j] = bias[n0 + wn*WTN + j*16 + l16];

    #pragma unroll
    for (int i = 0; i < NMT; ++i) {
        int row_base = wm*WTM + i*16 + quad*4;
        #pragma unroll
        for (int j = 0; j < NNT; ++j) {
            int col = wn*WTN + j*16 + l16;
            #pragma unroll
            for (int r = 0; r < 4; ++r)
                E[(size_t)(row_base + r)*(BN+4) + col] =
                    (_Float16)elu_f(acc[i][j][r] + bv[j]);
        }
    }
    __syncthreads();

    #pragma unroll
    for (int e = tid; e < P*C4; e += 256) {
        int ul = e / C4;
        int c4 = e - ul*C4;
        int pu = pu0 + ul;
        int u  = pu & vmask_out;
        const float* w = dwt + u*3;
        f16x4 a0 = *(const f16x4*)&E[(size_t)(ul*3 + 0)*(BN+4) + c4*4];
        f16x4 a1 = *(const f16x4*)&E[(size_t)(ul*3 + 1)*(BN+4) + c4*4];
        f16x4 a2 = *(const f16x4*)&E[(size_t)(ul*3 + 2)*(BN+4) + c4*4];
        float ox = w[0]*(float)a0[0] + w[1]*(float)a1[0] + w[2]*(float)a2[0];
        float oy = w[0]*(float)a0[1] + w[1]*(float)a1[1] + w[2]*(float)a2[1];
        float oz = w[0]*(float)a0[2] + w[1]*(float)a1[2] + w[2]*(float)a2[2];
        float ow = w[0]*(float)a0[3] + w[1]*(float)a1[3] + w[2]*(float)a2[3];
        if (OUT_HALF) {
            f16x4 h; h[0]=(_Float16)ox; h[1]=(_Float16)oy; h[2]=(_Float16)oz; h[3]=(_Float16)ow;
            *(f16x4*)&((_Float16*)outv)[(size_t)pu*C_OUT + n0 + c4*4] = h;
        } else {
            float4 o; o.x=ox; o.y=oy; o.z=oz; o.w=ow;
            *(float4*)&((float*)outv)[(size_t)pu*C_OUT + n0 + c4*4] = o;
        }
    }
}

// ---------------- FC1: atomic-free split-K (ks=256, k-chunk 128) ----------------
__global__ __launch_bounds__(256)
void fc1_partial(const float* __restrict__ xflat, const float* __restrict__ Wl1,
                 float* __restrict__ partial)
{
    __shared__ float sb[8704];
    const int tid = threadIdx.x;
    const int n4 = tid & 31;
    const int kq = (tid >> 5) & 3;
    const int mh = tid >> 7;
    const int nt = blockIdx.x;
    const int ks = blockIdx.y;
    const int kbase = ks * 128;

    for (int e = tid; e < 1024; e += 256) {
        int m = e >> 5, k4 = e & 31;
        *(float4*)&sb[m*128 + k4*4] = *(const float4*)&xflat[(size_t)m*32768 + kbase + k4*4];
    }
    __syncthreads();

    float acc[16][4];
    #pragma unroll
    for (int m = 0; m < 16; ++m)
        #pragma unroll
        for (int c = 0; c < 4; ++c) acc[m][c] = 0.0f;

    const float* Wb = Wl1 + (size_t)(kbase + kq*32)*512 + nt*128 + n4*4;
    #pragma unroll 2
    for (int i = 0; i < 32; i += 4) {
        float4 w0 = *(const float4*)(Wb + (size_t)(i+0)*512);
        float4 w1 = *(const float4*)(Wb + (size_t)(i+1)*512);
        float4 w2 = *(const float4*)(Wb + (size_t)(i+2)*512);
        float4 w3 = *(const float4*)(Wb + (size_t)(i+3)*512);
        #pragma unroll
        for (int m = 0; m < 16; ++m) {
            float4 xv = *(const float4*)&sb[(mh*16 + m)*128 + kq*32 + i];
            acc[m][0] += xv.x*w0.x + xv.y*w1.x + xv.z*w2.x + xv.w*w3.x;
            acc[m][1] += xv.x*w0.y + xv.y*w1.y + xv.z*w2.y + xv.w*w3.y;
            acc[m][2] += xv.x*w0.z + xv.y*w1.z + xv.z*w2.z + xv.w*w3.z;
            acc[m][3] += xv.x*w0.w + xv.y*w1.w + xv.z*w2.w + xv.w*w3.w;
        }
    }
    __syncthreads();

    int slot = (mh*2 + (kq >> 1))*32 + n4;
    if (kq & 1) {
        #pragma unroll
        for (int m = 0; m < 16; ++m)
            *(float4*)&sb[slot*68 + m*4] = *(float4*)&acc[m][0];
    }
    __syncthreads();
    if (!(kq & 1)) {
        #pragma unroll
        for (int m = 0; m < 16; ++m) {
            float4 v = *(const float4*)&sb[slot*68 + m*4];
            acc[m][0] += v.x; acc[m][1] += v.y; acc[m][2] += v.z; acc[m][3] += v.w;
        }
    }
    __syncthreads();
    int slot2 = mh*32 + n4;
    if (kq == 2) {
        #pragma unroll
        for (int m = 0; m < 16; ++m)
            *(float4*)&sb[slot2*68 + m*4] = *(float4*)&acc[m][0];
    }
    __syncthreads();
    if (kq == 0) {
        float* pb = partial + ((size_t)(ks*4 + nt)*32 + mh*16)*128 + n4*4;
        #pragma unroll
        for (int m = 0; m < 16; ++m) {
            float4 v = *(const float4*)&sb[slot2*68 + m*4];
            float4 o;
            o.x = acc[m][0] + v.x; o.y = acc[m][1] + v.y;
            o.z = acc[m][2] + v.z; o.w = acc[m][3] + v.w;
            *(float4*)(pb + (size_t)m*128) = o;
        }
    }
}

__global__ __launch_bounds__(256)
void fc1_reduce(const float* __restrict__ partial, const float* __restrict__ bl1,
                float* __restrict__ hout)
{
    int i = blockIdx.x * 256 + threadIdx.x;
    int m = i >> 9, n = i & 511;
    int nt = n >> 7, nl = n & 127;
    const float* p = partial + ((size_t)nt*32 + m)*128 + nl;
    float s = 0.0f;
    #pragma unroll 8
    for (int ks = 0; ks < 256; ++ks)
        s += p[(size_t)ks*4*4096];
    hout[i] = elu_f(s + bl1[n]);
}

__global__ __launch_bounds__(64)
void fc2_kernel(const float* __restrict__ h, const float* __restrict__ Wl2,
                const float* __restrict__ bl2, float* __restrict__ y)
{
    int m = blockIdx.x;
    int n = threadIdx.x;
    float s = bl2[n];
    for (int k = 0; k < 512; ++k)
        s += h[(size_t)m*512 + k] * Wl2[(size_t)k*64 + n];
    y[(size_t)m*64 + n] = s;
}

extern "C" void kernel_launch(void* const* d_in, const int* in_sizes, int n_in,
                              void* d_out, int out_size, void* d_ws, size_t ws_size,
                              hipStream_t stream)
{
    (void)in_sizes; (void)n_in; (void)out_size; (void)ws_size;

    const float* x0 = (const float*)d_in[0];
    const int*   sp[4]; const int* didx[4]; const float* dwp[4];
    const float* Wp[4]; const float* bp[4];
    for (int i = 0; i < 4; ++i) {
        sp[i]   = (const int*)  d_in[1 + i*5 + 0];
        didx[i] = (const int*)  d_in[1 + i*5 + 1];
        dwp[i]  = (const float*)d_in[1 + i*5 + 2];
        Wp[i]   = (const float*)d_in[1 + i*5 + 3];
        bp[i]   = (const float*)d_in[1 + i*5 + 4];
    }
    const float* Wl1 = (const float*)d_in[21];
    const float* bl1 = (const float*)d_in[22];
    const float* Wl2 = (const float*)d_in[23];
    const float* bl2 = (const float*)d_in[24];
    float* out = (float*)d_out;

    char* wsb = (char*)d_ws;
    float* persist      = (float*)wsb;                    // 4 MB   (32,128,256) fp32
    float* partial      = (float*)(wsb + (4<<20));        // 16.8 MB (1024 x 4096 f32)
    _Float16* xT        = (_Float16*)(wsb + (24<<20));    // 8 MB   (2 halves x 4 MB)
    _Float16* pooled0   = (_Float16*)(wsb + (32<<20));    // 16 MB  (32,8192,32) fp16
    _Float16* pooled1   = (_Float16*)(wsb + (48<<20));    // 8 MB   (32,2048,64) fp16
    _Float16* pooled2   = (_Float16*)(wsb + (56<<20));    // 4 MB   (32,512,128) fp16
    unsigned int* gidx0 = (unsigned int*)(wsb + (60<<20));// 0.75 MB
    _Float16* w0h       = (_Float16*)(wsb + (61<<20));
    _Float16* w1h       = w0h + 2048;
    _Float16* w2h       = w1h + 24576;
    _Float16* w3h       = w2h + 98304;

    prep_w0<<<8, 256, 0, stream>>>(Wp[0], w0h);
    prep_w< 384,  64,  32><<<( 24576 + 255)/256, 256, 0, stream>>>(Wp[1], w1h);
    prep_w< 768, 128,  64><<<( 98304 + 255)/256, 256, 0, stream>>>(Wp[2], w2h);
    prep_w<1536, 256,  32><<<(393216 + 255)/256, 256, 0, stream>>>(Wp[3], w3h);
    prep_gidx<<<768, 256, 0, stream>>>(didx[0], sp[0], gidx0);

    // L0: x transpose + batched-M conv0 (2 dispatches of 16 batches each)
    for (int h = 0; h < 2; ++h) {
        _Float16* xTh = xT + (size_t)h*2097152;
        prep_xT<<<512, 256, 0, stream>>>(x0 + (size_t)h*16*98304, xTh);
        conv0T<<<1024, 256, 0, stream>>>(xTh, gidx0, w0h, bp[0], dwp[0],
                                         pooled0 + (size_t)h*16*262144);
    }

    // L1: conv(32->64, K=384) + pool -> fp16 (32, 2048, 64)  [BN=32, 2048 blocks]
    conv_pool_mfma<32,64,64,32,4,1,true><<<dim3(1024, 2), 256, 0, stream>>>(
        pooled0, sp[1], w1h, bp[1], didx[1], dwp[1], pooled1, 13, 11, 2);

    // L2: conv(64->128, K=768) + pool -> fp16 (32, 512, 128) [BN=64, 1024 blocks]
    conv_pool_mfma<64,128,32,64,2,2,true><<<dim3(512, 2), 256, 0, stream>>>(
        pooled1, sp[2], w2h, bp[2], didx[2], dwp[2], pooled2, 11, 9, 2);

    // L3: conv(128->256, K=1536) + pool -> fp32 persist (32, 128, 256) [BN=32, 1024 blocks]
    conv_pool_mfma<128,256,32,32,2,2,false><<<dim3(128, 8), 256, 0, stream>>>(
        pooled2, sp[3], w3h, bp[3], didx[3], dwp[3], persist, 9, 7, 2);

    // FC1: (32,32768)@(32768,512), split-K partials then reduce+bias+ELU
    fc1_partial<<<dim3(4, 256), 256, 0, stream>>>(persist, Wl1, partial);
    fc1_reduce<<<64, 256, 0, stream>>>(partial, bl1, out);

    // FC2: (32,512)@(512,64) + bias -> d_out[16384:18432]
    fc2_kernel<<<32, 64, 0, stream>>>(out, Wl2, bl2, out + 16384);
}

// Round 11
// 332.952 us; speedup vs baseline: 1.1518x; 1.1518x over previous
//
#include <hip/hip_runtime.h>
#include <cstdint>
#include <cstddef>

typedef _Float16 f16x8 __attribute__((ext_vector_type(8)));
typedef _Float16 f16x4 __attribute__((ext_vector_type(4)));
typedef float f32x4 __attribute__((ext_vector_type(4)));

static __device__ __forceinline__ float elu_f(float t) {
    return t > 0.0f ? t : expm1f(t);
}

// XCD-aware block -> pooled-vertex-tile remap (XCD = bid & 7 round-robin).
static __device__ __forceinline__ int block_pu0(int bid, int P, int vshift_out, int nbl)
{
    if (nbl < 0) return bid * P;
    int xcd  = bid & 7;
    int slot = bid >> 3;
    int nb   = slot & ((1 << nbl) - 1);
    int tile = slot >> nbl;
    return ((xcd + (nb << 3)) << vshift_out) + tile * P;
}

// ---------------- weight prep: fp32 [K][C_OUT] -> fp16 tiled [y][t][kc][n][8] ----------------
template<int KTOT, int C_OUT, int BN>
__global__ __launch_bounds__(256)
void prep_w(const float* __restrict__ W, _Float16* __restrict__ o)
{
    constexpr int KT = KTOT/64;
    int i = blockIdx.x * 256 + threadIdx.x;
    if (i >= KTOT*C_OUT) return;
    int j = i & 7;
    int rest = i >> 3;
    int n = rest % BN;
    int kc = (rest / BN) & 7;
    int t = (rest / (BN*8)) % KT;
    int y = rest / (BN*8*KT);
    int k = t*64 + kc*8 + j;
    o[i] = (_Float16)W[(size_t)k*C_OUT + y*BN + n];
}

// Level-0 weights: (36,32) -> padded K=64, k = s*4 + c layout, tile [kc][n][8]
__global__ __launch_bounds__(256)
void prep_w0(const float* __restrict__ W, _Float16* __restrict__ o)
{
    int i = blockIdx.x * 256 + threadIdx.x;
    if (i >= 2048) return;
    int j = i & 7;
    int n = (i >> 3) & 31;
    int kc = i >> 8;
    int k = kc*8 + j;
    int s = k >> 2, c = k & 3;
    float v = (s < 12 && c < 3) ? W[(size_t)(s*3 + c)*32 + n] : 0.0f;
    o[i] = (_Float16)v;
}

// ---------------- x transpose: (16,32768,3) fp32 -> (32768,16,4) fp16 ----------------
__global__ __launch_bounds__(256)
void prep_xT(const float* __restrict__ x, _Float16* __restrict__ xT)
{
    __shared__ _Float16 t[16][64*4 + 8];
    const int v0 = blockIdx.x * 64;
    const int tid = threadIdx.x;
    #pragma unroll
    for (int it = 0; it < 4; ++it) {
        int e = it*256 + tid;          // 16 b x 64 v
        int b = e >> 6, v = e & 63;
        const float* p = x + ((size_t)b*32768 + v0 + v)*3;
        f16x4 h;
        h[0] = (_Float16)p[0]; h[1] = (_Float16)p[1];
        h[2] = (_Float16)p[2]; h[3] = (_Float16)0.f;
        *(f16x4*)&t[b][v*4] = h;
    }
    __syncthreads();
    #pragma unroll
    for (int it = 0; it < 2; ++it) {
        int e = it*256 + tid;          // 64 v x 8 s
        int vl = e >> 3, s = e & 7;
        f16x4 a = *(const f16x4*)&t[2*s][vl*4];
        f16x4 b = *(const f16x4*)&t[2*s+1][vl*4];
        f16x8 h;
        h[0]=a[0]; h[1]=a[1]; h[2]=a[2]; h[3]=a[3];
        h[4]=b[0]; h[5]=b[1]; h[6]=b[2]; h[7]=b[3];
        *(f16x8*)&xT[((size_t)(v0+vl)*16 + s*2)*4] = h;
    }
}

// ---------------- index pre-compose: didx0 o spiral0 -> u16-pair table ----------------
__global__ __launch_bounds__(256)
void prep_gidx(const int* __restrict__ didx, const int* __restrict__ spiral,
               unsigned int* __restrict__ g)
{
    int i = blockIdx.x*256 + threadIdx.x;   // 24576 rows x 8
    if (i >= 24576*8) return;
    int q = i & 7;
    int row = i >> 3;
    unsigned int val = 0;
    if (q < 6) {
        int v = didx[row];
        unsigned int s0 = (unsigned int)spiral[v*12 + q*2];
        unsigned int s1 = (unsigned int)spiral[v*12 + q*2 + 1];
        val = s0 | (s1 << 16);
    }
    g[i] = val;
}

// ---------------- conv0+pool0, batched-M over 16 batches ----------------
__global__ __launch_bounds__(256)
void conv0T(const _Float16* __restrict__ xT, const unsigned int* __restrict__ gidx,
            const _Float16* __restrict__ Wp, const float* __restrict__ bias,
            const float* __restrict__ dwt, _Float16* __restrict__ out)
{
    __shared__ _Float16 Ep[4][512];        // per-wave 1 KB transpose buffer
    const int tid  = threadIdx.x;
    const int wave = tid >> 6;
    const int lane = tid & 63;
    const int quad = lane >> 4;
    const int l16  = lane & 15;
    const int u0   = blockIdx.x * 8 + wave * 2;   // 2 u per wave

    f16x8 bf[2][2];
    #pragma unroll
    for (int kt = 0; kt < 2; ++kt)
        #pragma unroll
        for (int nt = 0; nt < 2; ++nt)
            bf[kt][nt] = *(const f16x8*)&Wp[(((kt*4+quad)*32) + nt*16 + l16)*8];
    float bv[2] = { bias[l16], bias[16 + l16] };

    #pragma unroll
    for (int ui = 0; ui < 2; ++ui) {
        int u = u0 + ui;
        f32x4 pacc[2] = {{0.f,0.f,0.f,0.f},{0.f,0.f,0.f,0.f}};
        #pragma unroll
        for (int kp = 0; kp < 3; ++kp) {
            int r = u*3 + kp;
            unsigned int gp0 = gidx[r*8 + quad];
            unsigned int gp1 = gidx[r*8 + 4 + quad];
            f16x4 a0 = *(const f16x4*)&xT[(size_t)(gp0 & 0xffffu)*64 + l16*4];
            f16x4 a1 = *(const f16x4*)&xT[(size_t)(gp0 >> 16)*64 + l16*4];
            f16x4 a2 = *(const f16x4*)&xT[(size_t)(gp1 & 0xffffu)*64 + l16*4];
            f16x4 a3 = *(const f16x4*)&xT[(size_t)(gp1 >> 16)*64 + l16*4];
            f16x8 af0, af1;
            af0[0]=a0[0]; af0[1]=a0[1]; af0[2]=a0[2]; af0[3]=a0[3];
            af0[4]=a1[0]; af0[5]=a1[1]; af0[6]=a1[2]; af0[7]=a1[3];
            af1[0]=a2[0]; af1[1]=a2[1]; af1[2]=a2[2]; af1[3]=a2[3];
            af1[4]=a3[0]; af1[5]=a3[1]; af1[6]=a3[2]; af1[7]=a3[3];
            float dw = dwt[r];
            #pragma unroll
            for (int nt = 0; nt < 2; ++nt) {
                f32x4 m = {0.f,0.f,0.f,0.f};
                m = __builtin_amdgcn_mfma_f32_16x16x32_f16(af0, bf[0][nt], m, 0,0,0);
                m = __builtin_amdgcn_mfma_f32_16x16x32_f16(af1, bf[1][nt], m, 0,0,0);
                #pragma unroll
                for (int rr = 0; rr < 4; ++rr)
                    pacc[nt][rr] += dw * elu_f(m[rr] + bv[nt]);
            }
        }
        #pragma unroll
        for (int nt = 0; nt < 2; ++nt)
            #pragma unroll
            for (int rr = 0; rr < 4; ++rr)
                Ep[wave][(quad*4+rr)*32 + nt*16 + l16] = (_Float16)pacc[nt][rr];
        int b  = lane >> 2;
        int c8 = lane & 3;
        f16x8 rowv = *(const f16x8*)&Ep[wave][b*32 + c8*8];
        *(f16x8*)&out[(size_t)b*262144 + (size_t)u*32 + c8*8] = rowv;
    }
}

// ---------------- fused conv+pool, direct-to-register MFMA + SW pipeline ----------------
// K-loop is explicitly double-buffered: step s+1's A/B fragment loads are
// issued before step s's MFMAs so the ~200-300 cyc L2 gather latency overlaps
// matrix issue instead of serializing every step.
template<int C_IN, int C_OUT, int P, int BN, int WGM, int WGN, bool OUT_HALF>
__global__ __launch_bounds__(256)
void conv_pool_mfma(const _Float16* __restrict__ x, const int* __restrict__ spiral,
                    const _Float16* __restrict__ Wp, const float* __restrict__ bias,
                    const int* __restrict__ didx, const float* __restrict__ dwt,
                    void* __restrict__ outv, int vshift_in, int vshift_out, int nbl)
{
    constexpr int R    = 3*P;
    constexpr int KTOT = 12*C_IN;
    constexpr int KT   = KTOT/64;
    constexpr int NST  = KT*2;           // number of K=32 steps
    constexpr int WTM  = R/WGM;
    constexpr int WTN  = BN/WGN;
    constexpr int NMT  = WTM/16;
    constexpr int NNT  = WTN/16;
    constexpr int C4   = BN/4;
    static_assert(WTM % 16 == 0 && WTN % 16 == 0, "tile");
    static_assert(R <= 256 && (P*C4) % 256 == 0, "loops");

    __shared__ unsigned short gidx[R*12];
    __shared__ _Float16 E[R*(BN+4)];

    const int tid  = threadIdx.x;
    const int wave = tid >> 6;
    const int lane = tid & 63;
    const int quad = lane >> 4;
    const int l16  = lane & 15;
    const int wm   = wave / WGN;
    const int wn   = wave % WGN;
    const int pu0  = block_pu0(blockIdx.x, P, vshift_out, nbl);
    const int n0   = blockIdx.y * BN;
    const int vmask_out = (1 << vshift_out) - 1;
    const int base_in = (pu0 >> vshift_out) << vshift_in;

    if (tid < R) {
        int ul = tid / 3;
        int kp = tid - ul*3;
        int u  = (pu0 + ul) & vmask_out;
        int v  = didx[u*3 + kp];
        const int* svp = spiral + v*12;
        #pragma unroll
        for (int j = 0; j < 12; ++j) gidx[tid*12 + j] = (unsigned short)svp[j];
    }
    __syncthreads();

    f32x4 acc[NMT][NNT];
    #pragma unroll
    for (int i = 0; i < NMT; ++i)
        #pragma unroll
        for (int j = 0; j < NNT; ++j) acc[i][j] = (f32x4){0.f, 0.f, 0.f, 0.f};

    const _Float16* xb = x + (size_t)base_in * C_IN;

    auto loadStep = [&](int s, f16x8* af, f16x8* bf) {
        const int k0 = s*32;
        const int sv = k0 / C_IN;
        const int c  = (k0 & (C_IN-1)) + quad*8;
        #pragma unroll
        for (int i = 0; i < NMT; ++i) {
            int m_local = wm*WTM + i*16 + l16;
            int g = gidx[m_local*12 + sv];
            af[i] = *(const f16x8*)&xb[(size_t)g*C_IN + c];
        }
        const _Float16* wsrc = Wp + ((size_t)(blockIdx.y*NST + s)*4 + quad)*BN*8;
        #pragma unroll
        for (int j = 0; j < NNT; ++j) {
            int n_local = wn*WTN + j*16 + l16;
            bf[j] = *(const f16x8*)&wsrc[n_local*8];
        }
    };
    auto mfmaStep = [&](const f16x8* af, const f16x8* bf) {
        #pragma unroll
        for (int i = 0; i < NMT; ++i)
            #pragma unroll
            for (int j = 0; j < NNT; ++j)
                acc[i][j] = __builtin_amdgcn_mfma_f32_16x16x32_f16(
                    af[i], bf[j], acc[i][j], 0, 0, 0);
    };

    f16x8 afA[NMT], bfA[NNT], afB[NMT], bfB[NNT];
    loadStep(0, afA, bfA);
    for (int st = 0; st < NST; st += 2) {
        loadStep(st + 1, afB, bfB);          // prefetch odd step
        mfmaStep(afA, bfA);
        if (st + 2 < NST) loadStep(st + 2, afA, bfA);   // prefetch next even step
        mfmaStep(afB, bfB);
    }

    float bv[NNT];
    #pragma unroll
    for (int j = 0; j < NNT; ++j)
        bv[j] = bias[n0 + wn*WTN + j*16 + l16];

    #pragma unroll
    for (int i = 0; i < NMT; ++i) {
        int row_base = wm*WTM + i*16 + quad*4;
        #pragma unroll
        for (int j = 0; j < NNT; ++j) {
            int col = wn*WTN + j*16 + l16;
            #pragma unroll
            for (int r = 0; r < 4; ++r)
                E[(size_t)(row_base + r)*(BN+4) + col] =
                    (_Float16)elu_f(acc[i][j][r] + bv[j]);
        }
    }
    __syncthreads();

    #pragma unroll
    for (int e = tid; e < P*C4; e += 256) {
        int ul = e / C4;
        int c4 = e - ul*C4;
        int pu = pu0 + ul;
        int u  = pu & vmask_out;
        const float* w = dwt + u*3;
        f16x4 a0 = *(const f16x4*)&E[(size_t)(ul*3 + 0)*(BN+4) + c4*4];
        f16x4 a1 = *(const f16x4*)&E[(size_t)(ul*3 + 1)*(BN+4) + c4*4];
        f16x4 a2 = *(const f16x4*)&E[(size_t)(ul*3 + 2)*(BN+4) + c4*4];
        float ox = w[0]*(float)a0[0] + w[1]*(float)a1[0] + w[2]*(float)a2[0];
        float oy = w[0]*(float)a0[1] + w[1]*(float)a1[1] + w[2]*(float)a2[1];
        float oz = w[0]*(float)a0[2] + w[1]*(float)a1[2] + w[2]*(float)a2[2];
        float ow = w[0]*(float)a0[3] + w[1]*(float)a1[3] + w[2]*(float)a2[3];
        if (OUT_HALF) {
            f16x4 h; h[0]=(_Float16)ox; h[1]=(_Float16)oy; h[2]=(_Float16)oz; h[3]=(_Float16)ow;
            *(f16x4*)&((_Float16*)outv)[(size_t)pu*C_OUT + n0 + c4*4] = h;
        } else {
            float4 o; o.x=ox; o.y=oy; o.z=oz; o.w=ow;
            *(float4*)&((float*)outv)[(size_t)pu*C_OUT + n0 + c4*4] = o;
        }
    }
}

// ---------------- FC1: atomic-free split-K (ks=256, k-chunk 128) ----------------
__global__ __launch_bounds__(256)
void fc1_partial(const float* __restrict__ xflat, const float* __restrict__ Wl1,
                 float* __restrict__ partial)
{
    __shared__ float sb[8704];
    const int tid = threadIdx.x;
    const int n4 = tid & 31;
    const int kq = (tid >> 5) & 3;
    const int mh = tid >> 7;
    const int nt = blockIdx.x;
    const int ks = blockIdx.y;
    const int kbase = ks * 128;

    for (int e = tid; e < 1024; e += 256) {
        int m = e >> 5, k4 = e & 31;
        *(float4*)&sb[m*128 + k4*4] = *(const float4*)&xflat[(size_t)m*32768 + kbase + k4*4];
    }
    __syncthreads();

    float acc[16][4];
    #pragma unroll
    for (int m = 0; m < 16; ++m)
        #pragma unroll
        for (int c = 0; c < 4; ++c) acc[m][c] = 0.0f;

    const float* Wb = Wl1 + (size_t)(kbase + kq*32)*512 + nt*128 + n4*4;
    #pragma unroll 2
    for (int i = 0; i < 32; i += 4) {
        float4 w0 = *(const float4*)(Wb + (size_t)(i+0)*512);
        float4 w1 = *(const float4*)(Wb + (size_t)(i+1)*512);
        float4 w2 = *(const float4*)(Wb + (size_t)(i+2)*512);
        float4 w3 = *(const float4*)(Wb + (size_t)(i+3)*512);
        #pragma unroll
        for (int m = 0; m < 16; ++m) {
            float4 xv = *(const float4*)&sb[(mh*16 + m)*128 + kq*32 + i];
            acc[m][0] += xv.x*w0.x + xv.y*w1.x + xv.z*w2.x + xv.w*w3.x;
            acc[m][1] += xv.x*w0.y + xv.y*w1.y + xv.z*w2.y + xv.w*w3.y;
            acc[m][2] += xv.x*w0.z + xv.y*w1.z + xv.z*w2.z + xv.w*w3.z;
            acc[m][3] += xv.x*w0.w + xv.y*w1.w + xv.z*w2.w + xv.w*w3.w;
        }
    }
    __syncthreads();

    int slot = (mh*2 + (kq >> 1))*32 + n4;
    if (kq & 1) {
        #pragma unroll
        for (int m = 0; m < 16; ++m)
            *(float4*)&sb[slot*68 + m*4] = *(float4*)&acc[m][0];
    }
    __syncthreads();
    if (!(kq & 1)) {
        #pragma unroll
        for (int m = 0; m < 16; ++m) {
            float4 v = *(const float4*)&sb[slot*68 + m*4];
            acc[m][0] += v.x; acc[m][1] += v.y; acc[m][2] += v.z; acc[m][3] += v.w;
        }
    }
    __syncthreads();
    int slot2 = mh*32 + n4;
    if (kq == 2) {
        #pragma unroll
        for (int m = 0; m < 16; ++m)
            *(float4*)&sb[slot2*68 + m*4] = *(float4*)&acc[m][0];
    }
    __syncthreads();
    if (kq == 0) {
        float* pb = partial + ((size_t)(ks*4 + nt)*32 + mh*16)*128 + n4*4;
        #pragma unroll
        for (int m = 0; m < 16; ++m) {
            float4 v = *(const float4*)&sb[slot2*68 + m*4];
            float4 o;
            o.x = acc[m][0] + v.x; o.y = acc[m][1] + v.y;
            o.z = acc[m][2] + v.z; o.w = acc[m][3] + v.w;
            *(float4*)(pb + (size_t)m*128) = o;
        }
    }
}

__global__ __launch_bounds__(256)
void fc1_reduce(const float* __restrict__ partial, const float* __restrict__ bl1,
                float* __restrict__ hout)
{
    int i = blockIdx.x * 256 + threadIdx.x;
    int m = i >> 9, n = i & 511;
    int nt = n >> 7, nl = n & 127;
    const float* p = partial + ((size_t)nt*32 + m)*128 + nl;
    float s = 0.0f;
    #pragma unroll 8
    for (int ks = 0; ks < 256; ++ks)
        s += p[(size_t)ks*4*4096];
    hout[i] = elu_f(s + bl1[n]);
}

__global__ __launch_bounds__(64)
void fc2_kernel(const float* __restrict__ h, const float* __restrict__ Wl2,
                const float* __restrict__ bl2, float* __restrict__ y)
{
    int m = blockIdx.x;
    int n = threadIdx.x;
    float s = bl2[n];
    for (int k = 0; k < 512; ++k)
        s += h[(size_t)m*512 + k] * Wl2[(size_t)k*64 + n];
    y[(size_t)m*64 + n] = s;
}

extern "C" void kernel_launch(void* const* d_in, const int* in_sizes, int n_in,
                              void* d_out, int out_size, void* d_ws, size_t ws_size,
                              hipStream_t stream)
{
    (void)in_sizes; (void)n_in; (void)out_size; (void)ws_size;

    const float* x0 = (const float*)d_in[0];
    const int*   sp[4]; const int* didx[4]; const float* dwp[4];
    const float* Wp[4]; const float* bp[4];
    for (int i = 0; i < 4; ++i) {
        sp[i]   = (const int*)  d_in[1 + i*5 + 0];
        didx[i] = (const int*)  d_in[1 + i*5 + 1];
        dwp[i]  = (const float*)d_in[1 + i*5 + 2];
        Wp[i]   = (const float*)d_in[1 + i*5 + 3];
        bp[i]   = (const float*)d_in[1 + i*5 + 4];
    }
    const float* Wl1 = (const float*)d_in[21];
    const float* bl1 = (const float*)d_in[22];
    const float* Wl2 = (const float*)d_in[23];
    const float* bl2 = (const float*)d_in[24];
    float* out = (float*)d_out;

    char* wsb = (char*)d_ws;
    float* persist      = (float*)wsb;                    // 4 MB   (32,128,256) fp32
    float* partial      = (float*)(wsb + (4<<20));        // 16.8 MB (1024 x 4096 f32)
    _Float16* xT        = (_Float16*)(wsb + (24<<20));    // 8 MB   (2 halves x 4 MB)
    _Float16* pooled0   = (_Float16*)(wsb + (32<<20));    // 16 MB  (32,8192,32) fp16
    _Float16* pooled1   = (_Float16*)(wsb + (48<<20));    // 8 MB   (32,2048,64) fp16
    _Float16* pooled2   = (_Float16*)(wsb + (56<<20));    // 4 MB   (32,512,128) fp16
    unsigned int* gidx0 = (unsigned int*)(wsb + (60<<20));// 0.75 MB
    _Float16* w0h       = (_Float16*)(wsb + (61<<20));
    _Float16* w1h       = w0h + 2048;
    _Float16* w2h       = w1h + 24576;
    _Float16* w3h       = w2h + 98304;

    prep_w0<<<8, 256, 0, stream>>>(Wp[0], w0h);
    prep_w< 384,  64,  64><<<( 24576 + 255)/256, 256, 0, stream>>>(Wp[1], w1h);
    prep_w< 768, 128, 128><<<( 98304 + 255)/256, 256, 0, stream>>>(Wp[2], w2h);
    prep_w<1536, 256,  64><<<(393216 + 255)/256, 256, 0, stream>>>(Wp[3], w3h);
    prep_gidx<<<768, 256, 0, stream>>>(didx[0], sp[0], gidx0);

    // L0: x transpose + batched-M conv0 (2 dispatches of 16 batches each)
    for (int h = 0; h < 2; ++h) {
        _Float16* xTh = xT + (size_t)h*2097152;
        prep_xT<<<512, 256, 0, stream>>>(x0 + (size_t)h*16*98304, xTh);
        conv0T<<<1024, 256, 0, stream>>>(xTh, gidx0, w0h, bp[0], dwp[0],
                                         pooled0 + (size_t)h*16*262144);
    }

    // L1: conv(32->64, K=384) + pool -> fp16 (32, 2048, 64)   [R9 config]
    conv_pool_mfma<32,64,64,64,4,1,true><<<1024, 256, 0, stream>>>(
        pooled0, sp[1], w1h, bp[1], didx[1], dwp[1], pooled1, 13, 11, 2);

    // L2: conv(64->128, K=768) + pool -> fp16 (32, 512, 128)  [R9 config]
    conv_pool_mfma<64,128,32,128,2,2,true><<<512, 256, 0, stream>>>(
        pooled1, sp[2], w2h, bp[2], didx[2], dwp[2], pooled2, 11, 9, 2);

    // L3: conv(128->256, K=1536) + pool -> fp32 persist (32, 128, 256) [R9 config]
    conv_pool_mfma<128,256,32,64,2,2,false><<<dim3(128, 4), 256, 0, stream>>>(
        pooled2, sp[3], w3h, bp[3], didx[3], dwp[3], persist, 9, 7, 2);

    // FC1: (32,32768)@(32768,512), split-K partials then reduce+bias+ELU
    fc1_partial<<<dim3(4, 256), 256, 0, stream>>>(persist, Wl1, partial);
    fc1_reduce<<<64, 256, 0, stream>>>(partial, bl1, out);

    // FC2: (32,512)@(512,64) + bias -> d_out[16384:18432]
    fc2_kernel<<<32, 64, 0, stream>>>(out, Wl2, bl2, out + 16384);
}